// Round 9
// baseline (128.644 us; speedup 1.0000x reference)
//
#include <hip/hip_runtime.h>

#define BB 2
#define LL 4096
#define SS 4096
#define HH 8
#define DD 64
#define UU 45
#define SCALE 0.125f
#define NCH 32     // softmax/context chunks of 128 s
#define CHK 128
#define SPP 28     // sp pitch (16B-aligned, 8-way-max on b32 writes)

// ---------------------------------------------------------------------------
// K1: M[bh*L + l] = max_u(dot) - sum_u(dot)/S over 45 sampled keys.
// 16-lane slots, per-head float4 gather, width-16 shuffle reduce, bh in low
// 4 bits -> XCD pin (per-XCD K working set 2MB, L2-resident; FETCH ~19MB).
// ---------------------------------------------------------------------------
__global__ __launch_bounds__(256) void k_compute_M(
    const float* __restrict__ q, const float* __restrict__ k,
    const int* __restrict__ idx, float* __restrict__ M) {
  __shared__ int sidx[16 * UU];
  int tid = threadIdx.x;
  int bh = blockIdx.x & 15;            // low bits -> XCD pin
  int l0 = (blockIdx.x >> 4) << 4;     // 16 l per block
  for (int i = tid; i < 16 * UU; i += 256) sidx[i] = idx[(long)l0 * UU + i];
  __syncthreads();

  int slot = tid >> 4;    // which l within block
  int sub  = tid & 15;    // d-quarter
  int l = l0 + slot;
  int b = bh >> 3, h = bh & 7;

  const float4* qp = (const float4*)(q + (((long)b * LL + l) * HH + h) * DD);
  float4 qq = qp[sub];
  const float* kb = k + (long)b * SS * HH * DD + h * DD;

  float mx = -INFINITY, sm = 0.f;
  #pragma unroll 5
  for (int u = 0; u < UU; ++u) {
    int s = sidx[slot * UU + u];
    float4 kk4 = ((const float4*)(kb + (long)s * (HH * DD)))[sub];
    float p = qq.x * kk4.x + qq.y * kk4.y + qq.z * kk4.z + qq.w * kk4.w;
    #pragma unroll
    for (int off = 8; off; off >>= 1) p += __shfl_xor(p, off, 16);
    mx = fmaxf(mx, p);
    sm += p;
  }
  if (sub == 0) M[(long)bh * LL + l] = mx - sm * (1.0f / SS);
}

// ---------------------------------------------------------------------------
// K2: top-45 per (b,h) via 4-pass radix-select; jax.lax.top_k semantics.
// ---------------------------------------------------------------------------
__global__ __launch_bounds__(256) void k_topk(
    const float* __restrict__ M, int* __restrict__ Mtop) {
  __shared__ unsigned keys[LL];
  __shared__ int hist[256];
  __shared__ int wsum[4];
  __shared__ int sh_bin, sh_gtwin;
  __shared__ int ccount, ecount;
  __shared__ unsigned cand_key[64];
  __shared__ int cand_idx[64];
  __shared__ int elist[LL];

  int bh = blockIdx.x, tid = threadIdx.x;
  int lane = tid & 63, w = tid >> 6;
  const float* m = M + (long)bh * LL;
  for (int i = tid; i < LL; i += 256) {
    union { float f; unsigned u; } cv; cv.f = m[i];
    keys[i] = (cv.u & 0x80000000u) ? ~cv.u : (cv.u | 0x80000000u);
  }
  if (tid == 0) { ccount = 0; ecount = 0; }
  __syncthreads();

  unsigned prefix = 0, pmask = 0;
  int need = UU, above = 0;

  for (int shift = 24; shift >= 0; shift -= 8) {
    hist[tid] = 0;
    __syncthreads();
    #pragma unroll
    for (int j = 0; j < 16; ++j) {
      unsigned kk = keys[tid + (j << 8)];
      if ((kk & pmask) == prefix) atomicAdd(&hist[(kk >> shift) & 255], 1);
    }
    __syncthreads();
    int v = hist[tid];
    int sfx = v;
    #pragma unroll
    for (int st = 1; st < 64; st <<= 1) {
      int o = __shfl_down(sfx, st, 64);
      if (lane + st < 64) sfx += o;
    }
    if (lane == 0) wsum[w] = sfx;
    __syncthreads();
    for (int t = w + 1; t < 4; ++t) sfx += wsum[t];
    int gt = sfx - v;
    if (gt < need && sfx >= need) {
      sh_bin = tid;
      sh_gtwin = gt;
    }
    __syncthreads();
    prefix |= ((unsigned)sh_bin << shift);
    pmask  |= (255u << shift);
    need  -= sh_gtwin;
    above += sh_gtwin;
    __syncthreads();
  }
  unsigned T = prefix;

  #pragma unroll
  for (int j = 0; j < 16; ++j) {
    int i = tid + (j << 8);
    unsigned kk = keys[i];
    if (kk > T)      { int p = atomicAdd(&ccount, 1); cand_key[p] = kk; cand_idx[p] = i; }
    else if (kk == T){ int p = atomicAdd(&ecount, 1); elist[p] = i; }
  }
  __syncthreads();
  int nc = ccount, ne = ecount;
  for (int t = tid; t < nc; t += 256) {
    unsigned kk = cand_key[t]; int ii = cand_idx[t]; int r = 0;
    for (int j = 0; j < nc; ++j)
      r += (cand_key[j] > kk) || (cand_key[j] == kk && cand_idx[j] < ii);
    Mtop[bh * UU + r] = ii;
  }
  for (int t = tid; t < ne; t += 256) {
    int ii = elist[t]; int r = 0;
    for (int j = 0; j < ne; ++j) r += (elist[j] < ii);
    if (r < need) Mtop[bh * UU + above + r] = ii;
  }
}

// ---------------------------------------------------------------------------
// KF: fused scores + chunk-softmax + context-partial, u-split for occupancy.
// grid (NCH, 2, B*H); block handles 23 (uh=0) or 22 (uh=1) u-rows x 128 s.
// LDS ~20KB -> 4+ blocks/CU resident (vs 2 at 46KB). qr region reused for
// the cross-wave acc combine.
// ---------------------------------------------------------------------------
__global__ __launch_bounds__(256) void k_fused(
    const float* __restrict__ q, const float* __restrict__ k,
    const float* __restrict__ v, const int* __restrict__ Mtop,
    float* __restrict__ attn, float* __restrict__ part,
    float2* __restrict__ stats) {
  __shared__ float qr[23 * DD];         // 1472 f; reused as acc staging
  __shared__ float sp[CHK * SPP];       // 3584 f
  __shared__ float gm[23], gl[23];

  int ch = blockIdx.x, uh = blockIdx.y, bh = blockIdx.z;
  int b = bh >> 3, h = bh & 7;
  int ubase = uh * 23;
  int ucount = uh ? 22 : 23;
  int tid = threadIdx.x;
  int lane = tid & 63, w = tid >> 6;
  int s0 = ch * CHK;

  for (int i = tid; i < ucount * DD; i += 256) {
    int uu = i >> 6, d = i & 63;
    int l = Mtop[bh * UU + ubase + uu];
    qr[i] = q[(((long)b * LL + l) * HH + h) * DD + d];
  }
  __syncthreads();

  // P1: scores for this u-range (thread = (s, u-half-of-range))
  {
    int sl = tid & 127, ph = tid >> 7;
    float4 kr[16];
    const float4* kp = (const float4*)(k + (((long)b * SS + s0 + sl) * HH + h) * DD);
    #pragma unroll
    for (int j = 0; j < 16; ++j) kr[j] = kp[j];
    int mid = (ucount + 1) >> 1;
    int u_lo = ph ? mid : 0, u_hi = ph ? ucount : mid;
    for (int uu = u_lo; uu < u_hi; ++uu) {
      const float4* qp = (const float4*)(qr + uu * DD);
      float acc = 0.f;
      #pragma unroll
      for (int j = 0; j < 16; ++j) {
        float4 qq = qp[j];
        acc += qq.x * kr[j].x + qq.y * kr[j].y + qq.z * kr[j].z + qq.w * kr[j].w;
      }
      sp[sl * SPP + uu] = acc * SCALE;
    }
  }
  __syncthreads();

  // P2a: per-u chunk max
  for (int uu = w; uu < ucount; uu += 4) {
    float a0 = sp[lane * SPP + uu];
    float a1 = sp[(lane + 64) * SPP + uu];
    float mx = fmaxf(a0, a1);
    #pragma unroll
    for (int off = 32; off; off >>= 1) mx = fmaxf(mx, __shfl_xor(mx, off, 64));
    if (lane == 0) gm[uu] = mx;
  }
  __syncthreads();
  // P2b: exp apply + unnormalized attn write
  for (int i = tid; i < ucount * CHK; i += 256) {
    int uu = i >> 7, sl = i & 127;
    float p = __expf(sp[sl * SPP + uu] - gm[uu]);
    sp[sl * SPP + uu] = p;
    attn[((long)bh * UU + ubase + uu) * SS + s0 + sl] = p;
  }
  __syncthreads();
  // P2c: per-u chunk sum
  for (int uu = w; uu < ucount; uu += 4) {
    float a0 = sp[lane * SPP + uu];
    float a1 = sp[(lane + 64) * SPP + uu];
    float e = a0 + a1;
    #pragma unroll
    for (int off = 32; off; off >>= 1) e += __shfl_xor(e, off, 64);
    if (lane == 0) gl[uu] = e;
  }

  // P3: context accumulate (lane = d), wave-uniform b128 broadcasts
  float acc[23];
  #pragma unroll
  for (int uu = 0; uu < 23; ++uu) acc[uu] = 0.f;
  const float* vb = v + (long)b * SS * HH * DD + h * DD + lane;
  #pragma unroll 2
  for (int j = 0; j < 32; ++j) {
    int sl = (j << 2) + w;
    float vd = vb[(long)(s0 + sl) * (HH * DD)];
    const float* ar = sp + sl * SPP;
    #pragma unroll
    for (int g = 0; g < 5; ++g) {
      float4 aa = *(const float4*)(ar + g * 4);
      acc[g * 4 + 0] += aa.x * vd;
      acc[g * 4 + 1] += aa.y * vd;
      acc[g * 4 + 2] += aa.z * vd;
      acc[g * 4 + 3] += aa.w * vd;
    }
    acc[20] += ar[20] * vd;
    acc[21] += ar[21] * vd;
    if (ucount == 23) acc[22] += ar[22] * vd;
  }

  // combine 4 wave partials via qr region (sequential adds)
  __syncthreads();
  float* stg = qr;
  if (w == 0) { for (int uu = 0; uu < ucount; ++uu) stg[uu * DD + lane] = acc[uu]; }
  __syncthreads();
  if (w == 1) { for (int uu = 0; uu < ucount; ++uu) stg[uu * DD + lane] += acc[uu]; }
  __syncthreads();
  if (w == 2) { for (int uu = 0; uu < ucount; ++uu) stg[uu * DD + lane] += acc[uu]; }
  __syncthreads();
  if (w == 3) { for (int uu = 0; uu < ucount; ++uu) stg[uu * DD + lane] += acc[uu]; }
  __syncthreads();

  long base = ((long)bh * NCH + ch) * (UU * DD) + (long)ubase * DD;
  for (int i = tid; i < ucount * DD; i += 256) part[base + i] = stg[i];
  if (tid < ucount)
    stats[((long)bh * UU + ubase + tid) * NCH + ch] = make_float2(gm[tid], gl[tid]);
}

// ---------------------------------------------------------------------------
// KE: epilogue. blocks [0,720): rescale one attn row by e^{m_ch-M}/L.
//     blocks [720,900): ctx[e] = sum_ch part*e^{m_ch-M} / L.
// ---------------------------------------------------------------------------
__global__ __launch_bounds__(256) void k_epilogue(
    const float2* __restrict__ stats, const float* __restrict__ part,
    float* __restrict__ attn, float* __restrict__ ctx) {
  __shared__ float f[NCH];
  __shared__ float2 st_s[NCH];
  int bid = blockIdx.x, tid = threadIdx.x;
  if (bid < BB * HH * UU) {
    long row = bid;                     // bh*UU + u
    const float2* st = stats + row * NCH;
    if (tid < NCH) st_s[tid] = st[tid];
    __syncthreads();
    if (tid == 0) {
      float M = -INFINITY;
      #pragma unroll
      for (int c = 0; c < NCH; ++c) M = fmaxf(M, st_s[c].x);
      float L = 0.f;
      #pragma unroll
      for (int c = 0; c < NCH; ++c) L += st_s[c].y * __expf(st_s[c].x - M);
      float inv = 1.0f / L;
      #pragma unroll
      for (int c = 0; c < NCH; ++c) f[c] = __expf(st_s[c].x - M) * inv;
    }
    __syncthreads();
    float4* a = (float4*)(attn + row * SS);
    #pragma unroll
    for (int g = 0; g < 4; ++g) {
      int i4 = g * 256 + tid;           // float4 index, 32 per chunk
      float ff = f[i4 >> 5];
      float4 vv = a[i4];
      vv.x *= ff; vv.y *= ff; vv.z *= ff; vv.w *= ff;
      a[i4] = vv;
    }
  } else {
    int e = (bid - BB * HH * UU) * 256 + tid;   // < 46080
    int bh = e / (UU * DD);
    int r = e - bh * (UU * DD);
    int u = r >> 6;
    const float2* st = stats + ((long)bh * UU + u) * NCH;
    float M = -INFINITY;
    #pragma unroll
    for (int c = 0; c < NCH; ++c) M = fmaxf(M, st[c].x);
    float L = 0.f, s = 0.f;
    #pragma unroll
    for (int c = 0; c < NCH; ++c) {
      float ee = __expf(st[c].x - M);
      L += st[c].y * ee;
      s += part[((long)bh * NCH + c) * (UU * DD) + r] * ee;
    }
    ctx[e] = s / L;
  }
}

// --------------------- fallback path (small ws) ----------------------------
__global__ __launch_bounds__(256) void k_scores(
    const float* __restrict__ q, const float* __restrict__ k,
    const int* __restrict__ Mtop, float* __restrict__ attn) {
  __shared__ float qr[UU * DD];
  int bh = blockIdx.y;
  int b = bh >> 3, h = bh & 7;
  for (int i = threadIdx.x; i < UU * DD; i += 256) {
    int u = i >> 6, d = i & 63;
    int l = Mtop[bh * UU + u];
    qr[i] = q[(((long)b * LL + l) * HH + h) * DD + d];
  }
  __syncthreads();
  int s = blockIdx.x * 256 + threadIdx.x;
  float4 kr[16];
  const float4* kp = (const float4*)(k + (((long)b * SS + s) * HH + h) * DD);
  #pragma unroll
  for (int j = 0; j < 16; ++j) kr[j] = kp[j];
  for (int u = 0; u < UU; ++u) {
    const float4* qp = (const float4*)(qr + u * DD);
    float acc = 0.f;
    #pragma unroll
    for (int j = 0; j < 16; ++j) {
      float4 qq = qp[j];
      acc += qq.x * kr[j].x + qq.y * kr[j].y + qq.z * kr[j].z + qq.w * kr[j].w;
    }
    attn[((long)bh * UU + u) * SS + s] = acc * SCALE;
  }
}

__global__ __launch_bounds__(256) void k_softmax(float* __restrict__ attn) {
  __shared__ float red[256];
  long row = blockIdx.x;
  float* a = attn + row * SS;
  float v[16];
  float mx = -INFINITY;
  #pragma unroll
  for (int j = 0; j < 16; ++j) {
    v[j] = a[j * 256 + threadIdx.x];
    mx = fmaxf(mx, v[j]);
  }
  red[threadIdx.x] = mx;
  __syncthreads();
  for (int st = 128; st; st >>= 1) {
    if (threadIdx.x < st) red[threadIdx.x] = fmaxf(red[threadIdx.x], red[threadIdx.x + st]);
    __syncthreads();
  }
  mx = red[0];
  __syncthreads();
  float sm = 0.f;
  #pragma unroll
  for (int j = 0; j < 16; ++j) {
    v[j] = __expf(v[j] - mx);
    sm += v[j];
  }
  red[threadIdx.x] = sm;
  __syncthreads();
  for (int st = 128; st; st >>= 1) {
    if (threadIdx.x < st) red[threadIdx.x] += red[threadIdx.x + st];
    __syncthreads();
  }
  float inv = 1.0f / red[0];
  #pragma unroll
  for (int j = 0; j < 16; ++j) a[j * 256 + threadIdx.x] = v[j] * inv;
}

__global__ __launch_bounds__(256) void k_context_fb(
    const float* __restrict__ attn, const float* __restrict__ v,
    float* __restrict__ ctx) {
  __shared__ float red[4][DD];
  int row = blockIdx.x;
  int bh = row / UU;
  int b = bh >> 3, h = bh & 7;
  int lane = threadIdx.x & 63;
  int grp = threadIdx.x >> 6;
  const float* a = attn + (long)row * SS;
  float acc = 0.f;
  for (int s = grp; s < SS; s += 4)
    acc += a[s] * v[(((long)b * SS + s) * HH + h) * DD + lane];
  red[grp][lane] = acc;
  __syncthreads();
  if (grp == 0)
    ctx[(long)row * DD + lane] = red[0][lane] + red[1][lane] + red[2][lane] + red[3][lane];
}

extern "C" void kernel_launch(void* const* d_in, const int* in_sizes, int n_in,
                              void* d_out, int out_size, void* d_ws, size_t ws_size,
                              hipStream_t stream) {
  const float* q   = (const float*)d_in[0];
  const float* k   = (const float*)d_in[1];
  const float* v   = (const float*)d_in[2];
  const int*   idx = (const int*)d_in[3];

  float* out  = (float*)d_out;
  float* ctx  = out;                           // B*H*U*D = 46080 floats
  float* attn = out + (long)BB * HH * UU * DD; // B*H*U*S floats

  // Overlays on d_out (stream-ordered write-after-read):
  //  - M at start of attn region (consumed by topk before KF overwrites)
  //  - Mtop at start of ctx region (consumed by KF before KE writes ctx)
  float* M    = attn;
  int*   Mtop = (int*)ctx;

  k_compute_M<<<BB * HH * LL / 16, 256, 0, stream>>>(q, k, idx, M);
  k_topk<<<BB * HH, 256, 0, stream>>>(M, Mtop);

  size_t part_bytes  = (size_t)BB * HH * NCH * UU * DD * sizeof(float);   // 5898240
  size_t stats_bytes = (size_t)BB * HH * UU * NCH * sizeof(float2);       // 184320
  if (ws_size >= part_bytes + stats_bytes) {
    float*  part  = (float*)d_ws;
    float2* stats = (float2*)((char*)d_ws + part_bytes);
    k_fused<<<dim3(NCH, 2, BB * HH), 256, 0, stream>>>(q, k, v, Mtop, attn, part, stats);
    int nctx = (BB * HH * UU * DD) / 256;      // 180
    k_epilogue<<<BB * HH * UU + nctx, 256, 0, stream>>>(stats, part, attn, ctx);
  } else {
    k_scores<<<dim3(SS / 256, BB * HH), 256, 0, stream>>>(q, k, Mtop, attn);
    k_softmax<<<BB * HH * UU, 256, 0, stream>>>(attn);
    k_context_fb<<<BB * HH * UU, 256, 0, stream>>>(attn, v, ctx);
  }
}